// Round 4
// baseline (14547.215 us; speedup 1.0000x reference)
//
#include <hip/hip_runtime.h>

#define HDIM  128
#define G3    384
#define RPB   16
#define NTHR  512
#define NSTEP 256
#define NOUT  33
#define BROWS 8192
#define NBLK  (BROWS / RPB)      // 512 blocks -> 2 per CU
#define LOGP_ELEMS 69206016LL    // 8192*256*33
#define PRED_LD 34

typedef _Float16 half8 __attribute__((ext_vector_type(8)));
typedef float    f32x4 __attribute__((ext_vector_type(4)));

// ws layout: packed weights | fc pack | T1 | T0
#define WP_BYTES  589824         // 3 mats x 24 nt x 4 kc x 2 s x 1024 B
#define FP_BYTES  24576          // fc: 3 nt x 4 kc x 2 s x 1024 B

__device__ __forceinline__ float sigf(float x) { return 1.0f / (1.0f + __expf(-x)); }
__device__ __forceinline__ float tanh_fast(float x) { return 1.0f - 2.0f / (__expf(2.0f*x) + 1.0f); }

// ---------------- prep: gi0 tables (fp32) ----------------
__global__ void prep_kernel(const float* __restrict__ emb, const float* __restrict__ wih0,
                            const float* __restrict__ bih0, float* __restrict__ T1,
                            float* __restrict__ T0) {
    int a = blockIdx.x;          // 0..31
    int g = threadIdx.x;         // 0..383
    const float* e = emb + a * 127;
    const float* w = wih0 + g * HDIM;
    float s = bih0[g];
    for (int k = 0; k < 127; ++k) s += e[k] * w[k];
    T1[a * G3 + g] = s + w[127];
    if (a == 0) T0[g] = s;
}

// ---------------- prep: fp16 2-split B-fragment packing ----------------
// lane holds B[g = nt*16 + (lane&15)][k = kc*32 + (lane>>4)*8 + e]
__global__ void prep_pack(const float* __restrict__ whh0, const float* __restrict__ wih1,
                          const float* __restrict__ whh1, const float* __restrict__ fcw,
                          half8* __restrict__ WP) {
    int b = blockIdx.x;            // 0..74 : 0-71 weights, 72-74 fc
    int tid  = threadIdx.x;        // 256
    int lane = tid & 63;
    int kc   = tid >> 6;
    int nt, g, tile_base;
    const float* W;
    bool isfc = (b >= 72);
    if (!isfc) {
        int mat = b / 24; nt = b % 24;
        W = (mat == 0) ? whh0 : (mat == 1) ? wih1 : whh1;
        g = nt * 16 + (lane & 15);
        tile_base = ((mat * 24 + nt) * 4 + kc) * 2;
    } else {
        nt = b - 72;
        W = fcw;
        g = nt * 16 + (lane & 15);
        tile_base = (WP_BYTES / 1024) + (nt * 4 + kc) * 2;
    }
    int k = kc * 32 + (lane >> 4) * 8;
    half8 v1, v2;
#pragma unroll
    for (int e = 0; e < 8; ++e) {
        float x = (isfc && g >= NOUT) ? 0.0f : W[g * HDIM + k + e];
        _Float16 s1 = (_Float16)x;
        _Float16 s2 = (_Float16)(x - (float)s1);
        v1[e] = s1; v2[e] = s2;
    }
    WP[(size_t)tile_base * 64 + lane]       = v1;
    WP[(size_t)(tile_base + 1) * 64 + lane] = v2;
}

// ---------------- main decoder: register-resident weights ----------------
__launch_bounds__(NTHR, 4)
__global__ void decoder_kernel(const float* __restrict__ hid,
                               const float* __restrict__ T1, const float* __restrict__ T0,
                               const char* __restrict__ Bpg,
                               const float* __restrict__ bhh0,
                               const float* __restrict__ bih1, const float* __restrict__ bhh1,
                               const float* __restrict__ fcb,
                               float* __restrict__ out) {
    // LDS: h splits (2 x 8 KB), fc weights (24 KB), preds, acts  -> 43 KB, 2 blocks/CU
    __shared__ char  hs0[8192];        // split0 [16][256B] swizzled, split1 at +4096
    __shared__ char  hs1[8192];
    __shared__ char  fcl[FP_BYTES];
    __shared__ float preds[RPB * PRED_LD];
    __shared__ int   acts[RPB];

    const int tid  = threadIdx.x;
    const int row0 = blockIdx.x * RPB;
    float* lp = out;
    float* pp = out + LOGP_ELEMS;

    const int lane  = tid & 63;
    const int w     = tid >> 6;      // wave 0..7
    const int col   = lane & 15;
    const int q     = lane >> 4;
    const int akoff = q * 16;        // A-frag byte offset within 64B k-chunk
    const int j     = w * 16 + col;  // gate/hidden column owned by this lane

    // per-lane biases
    const float bR0 = bhh0[j], bZ0 = bhh0[128 + j], bN0 = bhh0[256 + j];
    const float iR1 = bih1[j], iZ1 = bih1[128 + j], iN1 = bih1[256 + j];
    const float hR1 = bhh1[j], hZ1 = bhh1[128 + j], hN1 = bhh1[256 + j];
    const int   fo  = w * 16 + col;
    const float fbias = (w < 3 && fo < NOUT) ? fcb[fo] : 0.0f;

    // ---- load ALL weight B-fragments into registers: [mat][ty][kc][split] ----
    half8 Wr[3][3][4][2];
#pragma unroll
    for (int mat = 0; mat < 3; ++mat)
#pragma unroll
        for (int ty = 0; ty < 3; ++ty)
#pragma unroll
            for (int kc = 0; kc < 4; ++kc)
#pragma unroll
                for (int s = 0; s < 2; ++s) {
                    int nt = ty * 8 + w;
                    Wr[mat][ty][kc][s] = *(const half8*)(Bpg +
                        (size_t)((((mat * 24 + nt) * 4 + kc) * 2 + s) * 1024) + lane * 16);
                }

    // ---- stage fc weights to LDS ----
    {
        const uint4* src = (const uint4*)(Bpg + WP_BYTES);
        uint4* dst = (uint4*)fcl;
        for (int i = tid; i < FP_BYTES / 16; i += NTHR) dst[i] = src[i];
    }

    // ---- init h0/h1 -> VGPRs + fp16 splits to LDS ----
    float h0v[4], h1v[4];
#pragma unroll
    for (int i = 0; i < 4; ++i) {
        int row = q * 4 + i;
        float v0 = hid[(size_t)(row0 + row) * HDIM + j];
        float v1 = hid[(size_t)BROWS * HDIM + (size_t)(row0 + row) * HDIM + j];
        h0v[i] = v0; h1v[i] = v1;
        int off = (row * 256 + j * 2) ^ ((row & 7) << 4);
        _Float16 s1 = (_Float16)v0, s2 = (_Float16)(v0 - (float)s1);
        *(_Float16*)(hs0 + off) = s1;
        *(_Float16*)(hs0 + 4096 + off) = s2;
        s1 = (_Float16)v1; s2 = (_Float16)(v1 - (float)s1);
        *(_Float16*)(hs1 + off) = s1;
        *(_Float16*)(hs1 + 4096 + off) = s2;
    }
    __syncthreads();

#define LGKM0() asm volatile("s_waitcnt lgkmcnt(0)" ::: "memory")
#define BAR()   __builtin_amdgcn_s_barrier()
#define MFMA(a, b, c) __builtin_amdgcn_mfma_f32_16x16x32_f16((a), (b), (c), 0, 0, 0)

#pragma unroll 1
    for (int t = 0; t < NSTEP; ++t) {
        // ---- T1/T0 gather for gates0 (issued early; latency hides under Phase A) ----
        float gi[3][4];
        if (t == 0) {
            float g0v = T0[j], g1v = T0[128 + j], g2v = T0[256 + j];
#pragma unroll
            for (int i = 0; i < 4; ++i) { gi[0][i] = g0v; gi[1][i] = g1v; gi[2][i] = g2v; }
        } else {
#pragma unroll
            for (int i = 0; i < 4; ++i) {
                const float* tab = T1 + acts[q * 4 + i] * G3;
                gi[0][i] = tab[j];
                gi[1][i] = tab[128 + j];
                gi[2][i] = tab[256 + j];
            }
        }

        // ---- Phase A: gh0 = h0.whh0^T + bhh0  AND  gh1 = h1.whh1^T + bhh1 ----
        f32x4 g0[3], ah[3];
        {
            f32x4 b0 = {bR0, bR0, bR0, bR0}, b1 = {bZ0, bZ0, bZ0, bZ0}, b2 = {bN0, bN0, bN0, bN0};
            g0[0] = b0; g0[1] = b1; g0[2] = b2;
            f32x4 c0 = {hR1, hR1, hR1, hR1}, c1 = {hZ1, hZ1, hZ1, hZ1}, c2 = {hN1, hN1, hN1, hN1};
            ah[0] = c0; ah[1] = c1; ah[2] = c2;
        }
#pragma unroll
        for (int kc = 0; kc < 4; ++kc) {
            int offA = (col * 256 + kc * 64 + akoff) ^ ((col & 7) << 4);
            half8 a1 = *(const half8*)(hs0 + offA);
            half8 a2 = *(const half8*)(hs0 + 4096 + offA);
#pragma unroll
            for (int ty = 0; ty < 3; ++ty) {
                g0[ty] = MFMA(a1, Wr[0][ty][kc][0], g0[ty]);
                g0[ty] = MFMA(a2, Wr[0][ty][kc][0], g0[ty]);
                g0[ty] = MFMA(a1, Wr[0][ty][kc][1], g0[ty]);
            }
            half8 c1 = *(const half8*)(hs1 + offA);
            half8 c2 = *(const half8*)(hs1 + 4096 + offA);
#pragma unroll
            for (int ty = 0; ty < 3; ++ty) {
                ah[ty] = MFMA(c1, Wr[2][ty][kc][0], ah[ty]);
                ah[ty] = MFMA(c2, Wr[2][ty][kc][0], ah[ty]);
                ah[ty] = MFMA(c1, Wr[2][ty][kc][1], ah[ty]);
            }
        }
        LGKM0(); BAR();   // BAR1: all hs0/hs1 reads done before rewrites

        // ---- gates0: h0_new, write hs0 splits ----
#pragma unroll
        for (int i = 0; i < 4; ++i) {
            float rg = sigf(gi[0][i] + g0[0][i]);
            float zg = sigf(gi[1][i] + g0[1][i]);
            float ng = tanh_fast(gi[2][i] + rg * g0[2][i]);
            float hnew = (1.0f - zg) * ng + zg * h0v[i];
            h0v[i] = hnew;
            int row = q * 4 + i;
            int off = (row * 256 + j * 2) ^ ((row & 7) << 4);
            _Float16 s1 = (_Float16)hnew, s2 = (_Float16)(hnew - (float)s1);
            *(_Float16*)(hs0 + off) = s1;
            *(_Float16*)(hs0 + 4096 + off) = s2;
        }
        LGKM0(); BAR();   // BAR2: hs0_new visible

        // ---- P3: gi1 = h0_new.wih1^T + bih1 ----
        f32x4 ai[3];
        {
            f32x4 b0 = {iR1, iR1, iR1, iR1}, b1 = {iZ1, iZ1, iZ1, iZ1}, b2 = {iN1, iN1, iN1, iN1};
            ai[0] = b0; ai[1] = b1; ai[2] = b2;
        }
#pragma unroll
        for (int kc = 0; kc < 4; ++kc) {
            int offA = (col * 256 + kc * 64 + akoff) ^ ((col & 7) << 4);
            half8 a1 = *(const half8*)(hs0 + offA);
            half8 a2 = *(const half8*)(hs0 + 4096 + offA);
#pragma unroll
            for (int ty = 0; ty < 3; ++ty) {
                ai[ty] = MFMA(a1, Wr[1][ty][kc][0], ai[ty]);
                ai[ty] = MFMA(a2, Wr[1][ty][kc][0], ai[ty]);
                ai[ty] = MFMA(a1, Wr[1][ty][kc][1], ai[ty]);
            }
        }

        // ---- gates1: h1_new, write hs1 splits (hs1 reads fenced by BAR1) ----
#pragma unroll
        for (int i = 0; i < 4; ++i) {
            float rg = sigf(ai[0][i] + ah[0][i]);
            float zg = sigf(ai[1][i] + ah[1][i]);
            float ng = tanh_fast(ai[2][i] + rg * ah[2][i]);
            float hnew = (1.0f - zg) * ng + zg * h1v[i];
            h1v[i] = hnew;
            int row = q * 4 + i;
            int off = (row * 256 + j * 2) ^ ((row & 7) << 4);
            _Float16 s1 = (_Float16)hnew, s2 = (_Float16)(hnew - (float)s1);
            *(_Float16*)(hs1 + off) = s1;
            *(_Float16*)(hs1 + 4096 + off) = s2;
        }
        LGKM0(); BAR();   // BAR3: hs1_new visible

        // ---- P6: preds = h1_new.fc_w^T + fc_b (waves 0-2) ----
        if (w < 3) {
            f32x4 acc = {fbias, fbias, fbias, fbias};
#pragma unroll
            for (int kc = 0; kc < 4; ++kc) {
                int offA = (col * 256 + kc * 64 + akoff) ^ ((col & 7) << 4);
                half8 a1 = *(const half8*)(hs1 + offA);
                half8 a2 = *(const half8*)(hs1 + 4096 + offA);
                half8 b1 = *(const half8*)(fcl + ((w * 4 + kc) * 2 + 0) * 1024 + lane * 16);
                half8 b2 = *(const half8*)(fcl + ((w * 4 + kc) * 2 + 1) * 1024 + lane * 16);
                acc = MFMA(a1, b1, acc);
                acc = MFMA(a2, b1, acc);
                acc = MFMA(a1, b2, acc);
            }
            if (fo < NOUT) {
#pragma unroll
                for (int i = 0; i < 4; ++i)
                    preds[(q * 4 + i) * PRED_LD + fo] = acc[i];
            }
        }
        LGKM0(); BAR();   // BAR4: preds visible

        // ---- P7: softmax/log_softmax + argmax (first-index) + store ----
        if (tid < 256) {
            int r = tid >> 4; int l16 = tid & 15; int c0 = l16 * 2;
            float v0 = preds[r * PRED_LD + c0];
            float v1 = preds[r * PRED_LD + c0 + 1];
            float bv; int bi;
            if (v0 >= v1) { bv = v0; bi = c0; } else { bv = v1; bi = c0 + 1; }
#pragma unroll
            for (int d = 1; d < 16; d <<= 1) {
                float ov = __shfl_xor(bv, d);
                int   oi = __shfl_xor(bi, d);
                if (ov > bv || (ov == bv && oi < bi)) { bv = ov; bi = oi; }
            }
            float e0 = __expf(v0 - bv), e1 = __expf(v1 - bv);
            float s = e0 + e1;
#pragma unroll
            for (int d = 1; d < 16; d <<= 1) s += __shfl_xor(s, d);
            float ls = __logf(s);
            float inv = 1.0f / s;
            size_t base = ((size_t)(row0 + r) * NSTEP + t) * NOUT;
            lp[base + c0]     = v0 - bv - ls;
            lp[base + c0 + 1] = v1 - bv - ls;
            pp[base + c0]     = e0 * inv;
            pp[base + c0 + 1] = e1 * inv;
            if (l16 == 0) {
                acts[r] = bi;
                lp[base + 32] = preds[r * PRED_LD + 32];  // raw duration logit stash
            }
        }
        LGKM0(); BAR();   // BAR5: acts visible for next step's gather
    }
#undef LGKM0
#undef BAR
#undef MFMA
}

// ---------------- duration softmax over time ----------------
__global__ void dur_kernel(float* __restrict__ out) {
    int wid  = threadIdx.x >> 6;
    int lane = threadIdx.x & 63;
    int row  = blockIdx.x * 4 + wid;
    float* lp = out;
    float* pp = out + LOGP_ELEMS;
    size_t base = (size_t)row * NSTEP * NOUT + 32;

    float v[4]; float m = -1e30f;
#pragma unroll
    for (int i = 0; i < 4; ++i) {
        v[i] = lp[base + (size_t)(lane * 4 + i) * NOUT];
        m = fmaxf(m, v[i]);
    }
#pragma unroll
    for (int d = 1; d < 64; d <<= 1) m = fmaxf(m, __shfl_xor(m, d));
    float e[4]; float s = 0.0f;
#pragma unroll
    for (int i = 0; i < 4; ++i) { e[i] = __expf(v[i] - m); s += e[i]; }
#pragma unroll
    for (int d = 1; d < 64; d <<= 1) s += __shfl_xor(s, d);
    float inv = 1.0f / s;
#pragma unroll
    for (int i = 0; i < 4; ++i) {
        size_t idx = base + (size_t)(lane * 4 + i) * NOUT;
        float dv = e[i] * inv;
        lp[idx] = dv;
        pp[idx] = dv;
    }
}

extern "C" void kernel_launch(void* const* d_in, const int* in_sizes, int n_in,
                              void* d_out, int out_size, void* d_ws, size_t ws_size,
                              hipStream_t stream) {
    const float* hid  = (const float*)d_in[1];
    const float* emb  = (const float*)d_in[2];
    const float* wih0 = (const float*)d_in[3];
    const float* whh0 = (const float*)d_in[4];
    const float* bih0 = (const float*)d_in[5];
    const float* bhh0 = (const float*)d_in[6];
    const float* wih1 = (const float*)d_in[7];
    const float* whh1 = (const float*)d_in[8];
    const float* bih1 = (const float*)d_in[9];
    const float* bhh1 = (const float*)d_in[10];
    const float* fcw  = (const float*)d_in[11];
    const float* fcb  = (const float*)d_in[12];

    char*  ws = (char*)d_ws;
    half8* WP = (half8*)ws;                               // WP_BYTES + FP_BYTES
    float* T1 = (float*)(ws + WP_BYTES + FP_BYTES);       // 32*384 f32
    float* T0 = T1 + 32 * G3;                             // 384 f32

    prep_kernel<<<32, 384, 0, stream>>>(emb, wih0, bih0, T1, T0);
    prep_pack<<<75, 256, 0, stream>>>(whh0, wih1, whh1, fcw, WP);

    decoder_kernel<<<NBLK, NTHR, 0, stream>>>(
        hid, T1, T0, ws, bhh0, bih1, bhh1, fcb, (float*)d_out);

    dur_kernel<<<BROWS / 4, 256, 0, stream>>>((float*)d_out);
}

// Round 5
// 7029.261 us; speedup vs baseline: 2.0695x; 2.0695x over previous
//
#include <hip/hip_runtime.h>

#define HDIM  128
#define G3    384
#define RPB   32
#define NTHR  512
#define NSTEP 256
#define NOUT  33
#define BROWS 8192
#define NBLK  (BROWS / RPB)      // 256 blocks -> 1 per CU
#define LOGP_ELEMS 69206016LL    // 8192*256*33
#define PRED_LD 34

typedef _Float16 half8 __attribute__((ext_vector_type(8)));
typedef float    f32x4 __attribute__((ext_vector_type(4)));

// ---------------- LDS byte layout (160128 <= 163840) ----------------
#define HS0_OFF   0              // h0 splits: [32 rows][256B] swz; split1 at +8192   (16384)
#define HS1_OFF   16384          //                                                   (16384)
#define BST_OFF   32768          // ring: 8 waves x 4 slots x 3072 B                  (98304)
#define FCW_OFF   131072         // fc weights 2-split: 3 nt x 4 kc x 2 s x 1024 B    (24576)
#define PRED_OFF  155648         // preds [32][34] f32                                 (4352)
#define ACTS_OFF  160000         // acts [32] int                                       (128)
#define LDS_BYTES 160128

// ---------------- ws layout ----------------
#define WP_BYTES  589824         // 3 mats x 24 nt x 4 kc x 2 s x 1024 B
#define FP_BYTES  24576

__device__ __forceinline__ float sigf(float x) { return 1.0f / (1.0f + __expf(-x)); }
__device__ __forceinline__ float tanh_fast(float x) { return 1.0f - 2.0f / (__expf(2.0f*x) + 1.0f); }

// ---------------- prep: gi0 tables (fp32) ----------------
__global__ void prep_kernel(const float* __restrict__ emb, const float* __restrict__ wih0,
                            const float* __restrict__ bih0, float* __restrict__ T1,
                            float* __restrict__ T0) {
    int a = blockIdx.x;          // 0..31
    int g = threadIdx.x;         // 0..383
    const float* e = emb + a * 127;
    const float* w = wih0 + g * HDIM;
    float s = bih0[g];
    for (int k = 0; k < 127; ++k) s += e[k] * w[k];
    T1[a * G3 + g] = s + w[127];
    if (a == 0) T0[g] = s;
}

// ---------------- prep: fp16 2-split B-fragment packing ----------------
__global__ void prep_pack(const float* __restrict__ whh0, const float* __restrict__ wih1,
                          const float* __restrict__ whh1, const float* __restrict__ fcw,
                          half8* __restrict__ WP) {
    int b = blockIdx.x;            // 0..74 : 0-71 weights, 72-74 fc
    int tid  = threadIdx.x;        // 256
    int lane = tid & 63;
    int kc   = tid >> 6;
    int nt, g, tile_base;
    const float* W;
    bool isfc = (b >= 72);
    if (!isfc) {
        int mat = b / 24; nt = b % 24;
        W = (mat == 0) ? whh0 : (mat == 1) ? wih1 : whh1;
        g = nt * 16 + (lane & 15);
        tile_base = ((mat * 24 + nt) * 4 + kc) * 2;
    } else {
        nt = b - 72;
        W = fcw;
        g = nt * 16 + (lane & 15);
        tile_base = (WP_BYTES / 1024) + (nt * 4 + kc) * 2;
    }
    int k = kc * 32 + (lane >> 4) * 8;
    half8 v1, v2;
#pragma unroll
    for (int e = 0; e < 8; ++e) {
        float x = (isfc && g >= NOUT) ? 0.0f : W[g * HDIM + k + e];
        _Float16 s1 = (_Float16)x;
        _Float16 s2 = (_Float16)(x - (float)s1);
        v1[e] = s1; v2[e] = s2;
    }
    WP[(size_t)tile_base * 64 + lane]       = v1;
    WP[(size_t)(tile_base + 1) * 64 + lane] = v2;
}

// ---------------- main decoder: resident residual split + streamed main split ----------------
__launch_bounds__(NTHR, 2)
__global__ void decoder_kernel(const float* __restrict__ hid,
                               const float* __restrict__ T1, const float* __restrict__ T0,
                               const char* __restrict__ Bpg,
                               const float* __restrict__ bhh0,
                               const float* __restrict__ bih1, const float* __restrict__ bhh1,
                               const float* __restrict__ fcb,
                               float* __restrict__ out) {
    extern __shared__ char smraw[];
    char*  hs0   = smraw + HS0_OFF;
    char*  hs1   = smraw + HS1_OFF;
    char*  bst   = smraw + BST_OFF;
    char*  fcl   = smraw + FCW_OFF;
    float* preds = (float*)(smraw + PRED_OFF);
    int*   acts  = (int*)(smraw + ACTS_OFF);

    const int tid  = threadIdx.x;
    const int row0 = blockIdx.x * RPB;
    float* lp = out;
    float* pp = out + LOGP_ELEMS;

    const int lane  = tid & 63;
    const int w     = tid >> 6;      // wave 0..7
    const int col   = lane & 15;
    const int q     = lane >> 4;
    const int akoff = q * 16;        // A-frag byte offset within 64B k-chunk
    const int j     = w * 16 + col;  // gate/hidden column owned by this lane
    char* const mybuf = bst + (size_t)w * 12288;   // 4 slots x 3072 B

    // ---- resident residual (split-2) weight tiles: 36 x half8 = 144 VGPR ----
    half8 Wr2[3][3][4];
#pragma unroll
    for (int mat = 0; mat < 3; ++mat)
#pragma unroll
        for (int ty = 0; ty < 3; ++ty)
#pragma unroll
            for (int kc = 0; kc < 4; ++kc)
                Wr2[mat][ty][kc] = *(const half8*)(Bpg +
                    (size_t)((((mat * 24 + (ty * 8 + w)) * 4 + kc) * 2 + 1) * 1024) + lane * 16);
    // pin: opaque-asm touch prevents rematerialization-by-reload inside the loop
#pragma unroll
    for (int mat = 0; mat < 3; ++mat)
#pragma unroll
        for (int ty = 0; ty < 3; ++ty)
#pragma unroll
            for (int kc = 0; kc < 4; ++kc)
                asm volatile("" : "+v"(Wr2[mat][ty][kc]));

    // ---- stage fc weights to LDS ----
    {
        const uint4* src = (const uint4*)(Bpg + WP_BYTES);
        uint4* dst = (uint4*)fcl;
        for (int i = tid; i < FP_BYTES / 16; i += NTHR) dst[i] = src[i];
    }

    // ---- init h0/h1 -> VGPRs + fp16 splits to LDS ----
    float h0v[2][4], h1v[2][4];
#pragma unroll
    for (int Mt = 0; Mt < 2; ++Mt)
#pragma unroll
        for (int i = 0; i < 4; ++i) {
            int row = Mt * 16 + q * 4 + i;
            float v0 = hid[(size_t)(row0 + row) * HDIM + j];
            float v1 = hid[(size_t)BROWS * HDIM + (size_t)(row0 + row) * HDIM + j];
            h0v[Mt][i] = v0; h1v[Mt][i] = v1;
            int off = (row * 256 + j * 2) ^ ((row & 7) << 4);
            _Float16 s1 = (_Float16)v0, s2 = (_Float16)(v0 - (float)s1);
            *(_Float16*)(hs0 + off) = s1;
            *(_Float16*)(hs0 + 8192 + off) = s2;
            s1 = (_Float16)v1; s2 = (_Float16)(v1 - (float)s1);
            *(_Float16*)(hs1 + off) = s1;
            *(_Float16*)(hs1 + 8192 + off) = s2;
        }
    __syncthreads();

#define LGKM0() asm volatile("s_waitcnt lgkmcnt(0)" ::: "memory")
#define VMW()   asm volatile("s_waitcnt vmcnt(9)" ::: "memory")
#define BAR()   __builtin_amdgcn_s_barrier()
#define MFMA(a, b, c) __builtin_amdgcn_mfma_f32_16x16x32_f16((a), (b), (c), 0, 0, 0)

    // stream-chunk cc (0..11): mat = {0:cc<4, 2:cc<8, 1:else}, kc = cc&3, ring slot = cc&3 (12 % 4 == 0)
#define STAGE(cc_) do {                                                           \
        constexpr int cm_ = (cc_) % 12;                                           \
        constexpr int mat_ = (cm_ < 4) ? 0 : ((cm_ < 8) ? 2 : 1);                 \
        constexpr int kc_  = cm_ & 3;                                             \
        char* dst_ = mybuf + (size_t)((cc_) & 3) * 3072;                          \
        _Pragma("unroll")                                                         \
        for (int ty_ = 0; ty_ < 3; ++ty_) {                                       \
            const char* src_ = Bpg + (size_t)((((mat_ * 24 + (ty_ * 8 + w)) * 4 + kc_) * 2 + 0) * 1024) + lane * 16; \
            __builtin_amdgcn_global_load_lds((const unsigned int*)src_,           \
                                             (unsigned int*)(dst_ + ty_ * 1024), 16, 0, 0); \
        }                                                                         \
    } while (0)

    // one consume iteration: stage c+3, ungated resident-split MFMAs, vmcnt gate, streamed MFMAs
#define CHUNK(c_, HS_, ACC_, MAT_) do {                                           \
        STAGE((c_) + 3);                                                          \
        constexpr int kc_ = (c_) & 3;                                             \
        half8 a1_[2], a2_[2];                                                     \
        _Pragma("unroll")                                                         \
        for (int Mt_ = 0; Mt_ < 2; ++Mt_) {                                       \
            int row_ = Mt_ * 16 + col;                                            \
            int off_ = (row_ * 256 + kc_ * 64 + akoff) ^ ((row_ & 7) << 4);       \
            a1_[Mt_] = *(const half8*)((HS_) + off_);                             \
            a2_[Mt_] = *(const half8*)((HS_) + 8192 + off_);                      \
        }                                                                         \
        _Pragma("unroll")                                                         \
        for (int ty_ = 0; ty_ < 3; ++ty_)                                         \
            _Pragma("unroll")                                                     \
            for (int Mt_ = 0; Mt_ < 2; ++Mt_)                                     \
                ACC_[ty_][Mt_] = MFMA(a1_[Mt_], Wr2[MAT_][ty_][kc_], ACC_[ty_][Mt_]); \
        VMW();                                                                    \
        char* buf_ = mybuf + (size_t)((c_) & 3) * 3072;                           \
        _Pragma("unroll")                                                         \
        for (int ty_ = 0; ty_ < 3; ++ty_) {                                       \
            half8 b1_ = *(const half8*)(buf_ + ty_ * 1024 + lane * 16);           \
            _Pragma("unroll")                                                     \
            for (int Mt_ = 0; Mt_ < 2; ++Mt_) {                                   \
                ACC_[ty_][Mt_] = MFMA(a1_[Mt_], b1_, ACC_[ty_][Mt_]);             \
                ACC_[ty_][Mt_] = MFMA(a2_[Mt_], b1_, ACC_[ty_][Mt_]);             \
            }                                                                     \
        }                                                                         \
    } while (0)

    // prologue: stage chunks 0,1,2 into slots 0,1,2
    STAGE(0); STAGE(1); STAGE(2);

#pragma unroll 1
    for (int t = 0; t < NSTEP; ++t) {
        // ---- P1 + P4: gh0 (mat0, A=hs0 old) and gh1 (mat2, A=hs1 old) ----
        f32x4 g0[3][2], ah[3][2];
#pragma unroll
        for (int ty = 0; ty < 3; ++ty) {
            float bg = bhh0[ty * 128 + j];
            float bh = bhh1[ty * 128 + j];
            f32x4 vg = {bg, bg, bg, bg}, vh = {bh, bh, bh, bh};
            g0[ty][0] = vg; g0[ty][1] = vg;
            ah[ty][0] = vh; ah[ty][1] = vh;
        }
        CHUNK(0, hs0, g0, 0); CHUNK(1, hs0, g0, 0);
        CHUNK(2, hs0, g0, 0); CHUNK(3, hs0, g0, 0);
        CHUNK(4, hs1, ah, 2); CHUNK(5, hs1, ah, 2);
        CHUNK(6, hs1, ah, 2); CHUNK(7, hs1, ah, 2);
        LGKM0(); BAR();   // BAR1: all hs0/hs1 reads done

        // ---- gates0: h0_new, write hs0 splits (T-table gathered lazily) ----
#pragma unroll
        for (int Mt = 0; Mt < 2; ++Mt)
#pragma unroll
            for (int i = 0; i < 4; ++i) {
                int row = Mt * 16 + q * 4 + i;
                const float* tab = (t == 0) ? T0 : (T1 + acts[row] * G3);
                float ir = tab[j], iz = tab[128 + j], inn = tab[256 + j];
                float rg = sigf(ir + g0[0][Mt][i]);
                float zg = sigf(iz + g0[1][Mt][i]);
                float ng = tanh_fast(inn + rg * g0[2][Mt][i]);
                float hnew = (1.0f - zg) * ng + zg * h0v[Mt][i];
                h0v[Mt][i] = hnew;
                int off = (row * 256 + j * 2) ^ ((row & 7) << 4);
                _Float16 s1 = (_Float16)hnew, s2 = (_Float16)(hnew - (float)s1);
                *(_Float16*)(hs0 + off) = s1;
                *(_Float16*)(hs0 + 8192 + off) = s2;
            }
        LGKM0(); BAR();   // BAR2: hs0_new visible

        // ---- P3: gi1 (mat1, A=hs0 new) ----
        f32x4 ai[3][2];
#pragma unroll
        for (int ty = 0; ty < 3; ++ty) {
            float bi = bih1[ty * 128 + j];
            f32x4 vb = {bi, bi, bi, bi};
            ai[ty][0] = vb; ai[ty][1] = vb;
        }
        CHUNK(8, hs0, ai, 1);  CHUNK(9, hs0, ai, 1);
        CHUNK(10, hs0, ai, 1); CHUNK(11, hs0, ai, 1);

        // ---- gates1: h1_new, write hs1 splits (hs1 reads fenced by BAR1) ----
#pragma unroll
        for (int Mt = 0; Mt < 2; ++Mt)
#pragma unroll
            for (int i = 0; i < 4; ++i) {
                float rg = sigf(ai[0][Mt][i] + ah[0][Mt][i]);
                float zg = sigf(ai[1][Mt][i] + ah[1][Mt][i]);
                float ng = tanh_fast(ai[2][Mt][i] + rg * ah[2][Mt][i]);
                float hnew = (1.0f - zg) * ng + zg * h1v[Mt][i];
                h1v[Mt][i] = hnew;
                int row = Mt * 16 + q * 4 + i;
                int off = (row * 256 + j * 2) ^ ((row & 7) << 4);
                _Float16 s1 = (_Float16)hnew, s2 = (_Float16)(hnew - (float)s1);
                *(_Float16*)(hs1 + off) = s1;
                *(_Float16*)(hs1 + 8192 + off) = s2;
            }
        LGKM0(); BAR();   // BAR3: hs1_new visible

        // ---- fc: preds = h1_new.fc_w^T + fc_b (waves 0-5) ----
        if (w < 6) {
            int fnt = w >> 1, fMt = w & 1;
            int fo = fnt * 16 + col;
            float fb = (fo < NOUT) ? fcb[fo] : 0.0f;
            f32x4 acc = {fb, fb, fb, fb};
#pragma unroll
            for (int kc = 0; kc < 4; ++kc) {
                int row = fMt * 16 + col;
                int off = (row * 256 + kc * 64 + akoff) ^ ((row & 7) << 4);
                half8 a1 = *(const half8*)(hs1 + off);
                half8 a2 = *(const half8*)(hs1 + 8192 + off);
                half8 b1 = *(const half8*)(fcl + ((fnt * 4 + kc) * 2 + 0) * 1024 + lane * 16);
                half8 b2 = *(const half8*)(fcl + ((fnt * 4 + kc) * 2 + 1) * 1024 + lane * 16);
                acc = MFMA(a1, b1, acc);
                acc = MFMA(a2, b1, acc);
                acc = MFMA(a1, b2, acc);
            }
            if (fo < NOUT) {
#pragma unroll
                for (int i = 0; i < 4; ++i)
                    preds[(fMt * 16 + q * 4 + i) * PRED_LD + fo] = acc[i];
            }
        }
        LGKM0(); BAR();   // BAR4: preds visible

        // ---- P7: softmax/log_softmax + argmax (first-index) + store ----
        {
            int r = tid >> 4; int l16 = tid & 15; int c0 = l16 * 2;
            float v0 = preds[r * PRED_LD + c0];
            float v1 = preds[r * PRED_LD + c0 + 1];
            float bv; int bi;
            if (v0 >= v1) { bv = v0; bi = c0; } else { bv = v1; bi = c0 + 1; }
#pragma unroll
            for (int d = 1; d < 16; d <<= 1) {
                float ov = __shfl_xor(bv, d);
                int   oi = __shfl_xor(bi, d);
                if (ov > bv || (ov == bv && oi < bi)) { bv = ov; bi = oi; }
            }
            float e0 = __expf(v0 - bv), e1 = __expf(v1 - bv);
            float s = e0 + e1;
#pragma unroll
            for (int d = 1; d < 16; d <<= 1) s += __shfl_xor(s, d);
            float ls = __logf(s);
            float inv = 1.0f / s;
            size_t base = ((size_t)(row0 + r) * NSTEP + t) * NOUT;
            lp[base + c0]     = v0 - bv - ls;
            lp[base + c0 + 1] = v1 - bv - ls;
            pp[base + c0]     = e0 * inv;
            pp[base + c0 + 1] = e1 * inv;
            if (l16 == 0) {
                acts[r] = bi;
                lp[base + 32] = preds[r * PRED_LD + 32];  // raw duration logit stash
            }
        }
        LGKM0(); BAR();   // BAR5: acts visible for next step
    }
#undef STAGE
#undef CHUNK
#undef LGKM0
#undef VMW
#undef BAR
#undef MFMA
}

// ---------------- duration softmax over time ----------------
__global__ void dur_kernel(float* __restrict__ out) {
    int wid  = threadIdx.x >> 6;
    int lane = threadIdx.x & 63;
    int row  = blockIdx.x * 4 + wid;
    float* lp = out;
    float* pp = out + LOGP_ELEMS;
    size_t base = (size_t)row * NSTEP * NOUT + 32;

    float v[4]; float m = -1e30f;
#pragma unroll
    for (int i = 0; i < 4; ++i) {
        v[i] = lp[base + (size_t)(lane * 4 + i) * NOUT];
        m = fmaxf(m, v[i]);
    }
#pragma unroll
    for (int d = 1; d < 64; d <<= 1) m = fmaxf(m, __shfl_xor(m, d));
    float e[4]; float s = 0.0f;
#pragma unroll
    for (int i = 0; i < 4; ++i) { e[i] = __expf(v[i] - m); s += e[i]; }
#pragma unroll
    for (int d = 1; d < 64; d <<= 1) s += __shfl_xor(s, d);
    float inv = 1.0f / s;
#pragma unroll
    for (int i = 0; i < 4; ++i) {
        size_t idx = base + (size_t)(lane * 4 + i) * NOUT;
        float dv = e[i] * inv;
        lp[idx] = dv;
        pp[idx] = dv;
    }
}

extern "C" void kernel_launch(void* const* d_in, const int* in_sizes, int n_in,
                              void* d_out, int out_size, void* d_ws, size_t ws_size,
                              hipStream_t stream) {
    const float* hid  = (const float*)d_in[1];
    const float* emb  = (const float*)d_in[2];
    const float* wih0 = (const float*)d_in[3];
    const float* whh0 = (const float*)d_in[4];
    const float* bih0 = (const float*)d_in[5];
    const float* bhh0 = (const float*)d_in[6];
    const float* wih1 = (const float*)d_in[7];
    const float* whh1 = (const float*)d_in[8];
    const float* bih1 = (const float*)d_in[9];
    const float* bhh1 = (const float*)d_in[10];
    const float* fcw  = (const float*)d_in[11];
    const float* fcb  = (const float*)d_in[12];

    char*  ws = (char*)d_ws;
    half8* WP = (half8*)ws;                               // WP_BYTES + FP_BYTES
    float* T1 = (float*)(ws + WP_BYTES + FP_BYTES);       // 32*384 f32
    float* T0 = T1 + 32 * G3;                             // 384 f32

    prep_kernel<<<32, 384, 0, stream>>>(emb, wih0, bih0, T1, T0);
    prep_pack<<<75, 256, 0, stream>>>(whh0, wih1, whh1, fcw, WP);

    hipFuncSetAttribute((const void*)decoder_kernel,
                        hipFuncAttributeMaxDynamicSharedMemorySize, LDS_BYTES);
    decoder_kernel<<<NBLK, NTHR, LDS_BYTES, stream>>>(
        hid, T1, T0, ws, bhh0, bih1, bhh1, fcb, (float*)d_out);

    dur_kernel<<<BROWS / 4, 256, 0, stream>>>((float*)d_out);
}